// Round 2
// baseline (6832.475 us; speedup 1.0000x reference)
//
#include <hip/hip_runtime.h>

#define TT 8192      // tokens
#define HD 2048      // hidden
#define FFN 5632
#define NE 8
#define BK 32

// ffn1 tile
#define BM1 256
#define BN1 128
#define PSA1 2064    // fp16 elems per k-plane: 256*8 + 16 pad (stride 4128B ≡ 32 mod 128)
#define PSB1 1040    // 128*8 + 16 pad (2080B ≡ 32 mod 128)
// ffn2 tile
#define BM2 256
#define BN2 256
#define PS2  2064

typedef float f32x4 __attribute__((ext_vector_type(4)));
typedef float f32x16 __attribute__((ext_vector_type(16)));
typedef _Float16 f16x8 __attribute__((ext_vector_type(8)));

// workspace layout (bytes)
#define OFF_WR    0u          // 16384 f32
#define OFF_CNT   65536u      // 8 int
#define OFF_LISTS 66048u      // 8*8192 int
#define OFF_TOKW  328192u     // 16384 f32
#define OFF_ACT   1048576u    // 16384*5632 f16

__device__ __forceinline__ f16x8 cvt8(f32x4 a, f32x4 b) {
  f16x8 r;
  r[0] = (_Float16)a[0]; r[1] = (_Float16)a[1]; r[2] = (_Float16)a[2]; r[3] = (_Float16)a[3];
  r[4] = (_Float16)b[0]; r[5] = (_Float16)b[1]; r[6] = (_Float16)b[2]; r[7] = (_Float16)b[3];
  return r;
}

__global__ __launch_bounds__(256) void k_prep(const float* __restrict__ wg,
                                              const float* __restrict__ wge,
                                              float* __restrict__ wr) {
  int i = blockIdx.x * 256 + threadIdx.x;
  if (i < HD * NE) wr[i] = 0.5f * (wge[i] + wg[i]);
}

__global__ __launch_bounds__(256) void k_router(const float* __restrict__ x,
                                                const float* __restrict__ wr,
                                                float* __restrict__ logits,
                                                float* __restrict__ tokw,
                                                int* __restrict__ lists,
                                                int* __restrict__ cnt) {
  const int t = blockIdx.x, tid = threadIdx.x;
  const float* xr = x + (size_t)t * HD;
  float acc[NE];
#pragma unroll
  for (int e = 0; e < NE; ++e) acc[e] = 0.f;
  for (int h = tid; h < HD; h += 256) {
    float xv = xr[h];
    const float* w = wr + h * NE;
#pragma unroll
    for (int e = 0; e < NE; ++e) acc[e] = fmaf(xv, w[e], acc[e]);
  }
#pragma unroll
  for (int e = 0; e < NE; ++e)
#pragma unroll
    for (int off = 32; off; off >>= 1)
      acc[e] += __shfl_xor(acc[e], off, 64);
  __shared__ float red[4][NE];
  int wv = tid >> 6;
  if ((tid & 63) == 0)
    for (int e = 0; e < NE; ++e) red[wv][e] = acc[e];
  __syncthreads();
  if (tid == 0) {
    float l[NE];
#pragma unroll
    for (int e = 0; e < NE; ++e) l[e] = red[0][e] + red[1][e] + red[2][e] + red[3][e];
#pragma unroll
    for (int e = 0; e < NE; ++e) logits[(size_t)t * NE + e] = l[e];
    int i0 = 0;
    for (int e = 1; e < NE; ++e) if (l[e] > l[i0]) i0 = e;
    int i1 = -1;
    for (int e = 0; e < NE; ++e) if (e != i0 && (i1 < 0 || l[e] > l[i1])) i1 = e;
    float p1 = __expf(l[i1] - l[i0]);
    float s = 1.f + p1;
    tokw[t * 2]     = 1.f / s;
    tokw[t * 2 + 1] = p1 / s;
    int q0 = atomicAdd(&cnt[i0], 1);
    lists[i0 * TT + q0] = t * 2;
    int q1 = atomicAdd(&cnt[i1], 1);
    lists[i1 * TT + q1] = t * 2 + 1;
  }
}

// ---------------- Stage A: act = silu(x@fc1_1^T) * (x@fc1_2^T) -> fp16 -------------
// 8 waves as 4x2 over (BM1=256, BN1=128); wave tile 64x64 dual-matrix; mfma 32x32x16.
__global__ __launch_bounds__(512) void k_ffn1(const float* __restrict__ x,
                                              const float* __restrict__ fc11,
                                              const float* __restrict__ fc12,
                                              const int* __restrict__ lists,
                                              const int* __restrict__ cnt,
                                              _Float16* __restrict__ act) {
  const int rt = blockIdx.x, ct = blockIdx.y, e = blockIdx.z;
  const int count = cnt[e];
  if (rt * BM1 >= count) return;
  const int tid = threadIdx.x;

  __shared__ __align__(16) _Float16 As[2][4 * PSA1];
  __shared__ __align__(16) _Float16 B1s[2][4 * PSB1];
  __shared__ __align__(16) _Float16 B2s[2][4 * PSB1];
  __shared__ int row_pair[BM1];

  if (tid < BM1) {
    int rg = rt * BM1 + tid;
    row_pair[tid] = (rg < count) ? lists[e * TT + rg] : -1;
  }
  __syncthreads();

  // staging: chunk = 8 consecutive k at one row. A: 1024 chunks (2/thread), B: 512 (1/thread)
  const int sr0 = tid >> 2;          // 0..127
  const int skg = tid & 3;           // k-chunk within BK
  const int sc8 = skg * 8;
  const int sr1 = sr0 + 128;
  const int pr0 = row_pair[sr0], pr1 = row_pair[sr1];
  const float* pa0 = (pr0 >= 0) ? x + (size_t)(pr0 >> 1) * HD + sc8 : nullptr;
  const float* pa1 = (pr1 >= 0) ? x + (size_t)(pr1 >> 1) * HD + sc8 : nullptr;
  const float* pb1 = fc11 + ((size_t)e * FFN + (size_t)ct * BN1 + sr0) * HD + sc8;
  const float* pb2 = fc12 + ((size_t)e * FFN + (size_t)ct * BN1 + sr0) * HD + sc8;
  const int wA0 = skg * PSA1 + sr0 * 8;
  const int wA1 = skg * PSA1 + sr1 * 8;
  const int wB  = skg * PSB1 + sr0 * 8;

  const f32x4 z4 = {0.f, 0.f, 0.f, 0.f};
  f32x4 a00, a01, a10, a11, b10, b11, b20, b21;
  auto load_tile = [&](int k0) {
    a00 = pa0 ? *(const f32x4*)(pa0 + k0) : z4;
    a01 = pa0 ? *(const f32x4*)(pa0 + k0 + 4) : z4;
    a10 = pa1 ? *(const f32x4*)(pa1 + k0) : z4;
    a11 = pa1 ? *(const f32x4*)(pa1 + k0 + 4) : z4;
    b10 = *(const f32x4*)(pb1 + k0); b11 = *(const f32x4*)(pb1 + k0 + 4);
    b20 = *(const f32x4*)(pb2 + k0); b21 = *(const f32x4*)(pb2 + k0 + 4);
  };
  auto write_tile = [&](int buf) {
    *(f16x8*)&As[buf][wA0]  = cvt8(a00, a01);
    *(f16x8*)&As[buf][wA1]  = cvt8(a10, a11);
    *(f16x8*)&B1s[buf][wB]  = cvt8(b10, b11);
    *(f16x8*)&B2s[buf][wB]  = cvt8(b20, b21);
  };

  f32x16 acc1[2][2], acc2[2][2];
#pragma unroll
  for (int m = 0; m < 2; ++m)
#pragma unroll
    for (int n = 0; n < 2; ++n) {
      acc1[m][n] = (f32x16)0.f;
      acc2[m][n] = (f32x16)0.f;
    }

  const int lane = tid & 63, wv = tid >> 6;
  const int wrow = (wv >> 1) * 64;   // 0,64,128,192
  const int wcol = (wv & 1) * 64;    // 0,64
  const int frow = lane & 31;
  const int kq   = lane >> 5;        // k-chunk-of-8 within mfma K=16

  load_tile(0);
  write_tile(0);
  __syncthreads();

  const int NS = HD / BK;  // 64
  for (int ks = 0; ks < NS; ++ks) {
    int buf = ks & 1;
    if (ks + 1 < NS) load_tile((ks + 1) * BK);
#pragma unroll
    for (int ksub = 0; ksub < 2; ++ksub) {
      const int p = ksub * 2 + kq;
      f16x8 fa0 = *(const f16x8*)&As[buf][p * PSA1 + (wrow + frow) * 8];
      f16x8 fa1 = *(const f16x8*)&As[buf][p * PSA1 + (wrow + 32 + frow) * 8];
      f16x8 fb10 = *(const f16x8*)&B1s[buf][p * PSB1 + (wcol + frow) * 8];
      f16x8 fb11 = *(const f16x8*)&B1s[buf][p * PSB1 + (wcol + 32 + frow) * 8];
      f16x8 fb20 = *(const f16x8*)&B2s[buf][p * PSB1 + (wcol + frow) * 8];
      f16x8 fb21 = *(const f16x8*)&B2s[buf][p * PSB1 + (wcol + 32 + frow) * 8];
      acc1[0][0] = __builtin_amdgcn_mfma_f32_32x32x16_f16(fa0, fb10, acc1[0][0], 0, 0, 0);
      acc1[0][1] = __builtin_amdgcn_mfma_f32_32x32x16_f16(fa0, fb11, acc1[0][1], 0, 0, 0);
      acc1[1][0] = __builtin_amdgcn_mfma_f32_32x32x16_f16(fa1, fb10, acc1[1][0], 0, 0, 0);
      acc1[1][1] = __builtin_amdgcn_mfma_f32_32x32x16_f16(fa1, fb11, acc1[1][1], 0, 0, 0);
      acc2[0][0] = __builtin_amdgcn_mfma_f32_32x32x16_f16(fa0, fb20, acc2[0][0], 0, 0, 0);
      acc2[0][1] = __builtin_amdgcn_mfma_f32_32x32x16_f16(fa0, fb21, acc2[0][1], 0, 0, 0);
      acc2[1][0] = __builtin_amdgcn_mfma_f32_32x32x16_f16(fa1, fb20, acc2[1][0], 0, 0, 0);
      acc2[1][1] = __builtin_amdgcn_mfma_f32_32x32x16_f16(fa1, fb21, acc2[1][1], 0, 0, 0);
    }
    if (ks + 1 < NS) write_tile(buf ^ 1);
    __syncthreads();
  }

  // epilogue: silu(h1)*h2 -> fp16 act, scattered by pair id
#pragma unroll
  for (int mi = 0; mi < 2; ++mi) {
#pragma unroll
    for (int ni = 0; ni < 2; ++ni) {
      const int col = (size_t)ct * BN1 + wcol + ni * 32 + frow;
#pragma unroll
      for (int r = 0; r < 16; ++r) {
        int rl = wrow + mi * 32 + 4 * kq + (r & 3) + 8 * (r >> 2);
        int pr = row_pair[rl];
        if (pr >= 0) {
          float h1 = acc1[mi][ni][r], h2 = acc2[mi][ni][r];
          float sv = h1 / (1.f + __expf(-h1));
          act[(size_t)pr * FFN + col] = (_Float16)(sv * h2);
        }
      }
    }
  }
}

// ---------------- Stage B: out += w * (act @ fc2^T) --------------------------------
// 8 waves as 2x4 over (BM2=256, BN2=256); wave tile 128x64; mfma 32x32x16.
__global__ __launch_bounds__(512) void k_ffn2(const _Float16* __restrict__ act,
                                              const float* __restrict__ fc2,
                                              const int* __restrict__ lists,
                                              const int* __restrict__ cnt,
                                              const float* __restrict__ tokw,
                                              float* __restrict__ out) {
  const int rt = blockIdx.x, ct = blockIdx.y, e = blockIdx.z;
  const int count = cnt[e];
  if (rt * BM2 >= count) return;
  const int tid = threadIdx.x;

  __shared__ __align__(16) _Float16 As[2][4 * PS2];
  __shared__ __align__(16) _Float16 Bs[2][4 * PS2];
  __shared__ int row_pair[BM2];
  __shared__ float row_w[BM2];

  if (tid < BM2) {
    int rg = rt * BM2 + tid;
    int pr = (rg < count) ? lists[e * TT + rg] : -1;
    row_pair[tid] = pr;
    row_w[tid] = (pr >= 0) ? tokw[pr] : 0.f;
  }
  __syncthreads();

  const int sr0 = tid >> 2;          // 0..127
  const int skg = tid & 3;
  const int sc8 = skg * 8;
  const int sr1 = sr0 + 128;
  const int pr0 = row_pair[sr0], pr1 = row_pair[sr1];
  const _Float16* pa0 = (pr0 >= 0) ? act + (size_t)pr0 * FFN + sc8 : nullptr;
  const _Float16* pa1 = (pr1 >= 0) ? act + (size_t)pr1 * FFN + sc8 : nullptr;
  const float* pb0 = fc2 + ((size_t)e * HD + (size_t)ct * BN2 + sr0) * FFN + sc8;
  const float* pb1 = fc2 + ((size_t)e * HD + (size_t)ct * BN2 + sr1) * FFN + sc8;
  const int wA0 = skg * PS2 + sr0 * 8;
  const int wA1 = skg * PS2 + sr1 * 8;

  const f32x4 z4 = {0.f, 0.f, 0.f, 0.f};
  const f16x8 z8 = (f16x8)(_Float16)0;
  f16x8 la0, la1;
  f32x4 lb00, lb01, lb10, lb11;
  auto load_tile = [&](int k0) {
    la0 = pa0 ? *(const f16x8*)(pa0 + k0) : z8;
    la1 = pa1 ? *(const f16x8*)(pa1 + k0) : z8;
    lb00 = *(const f32x4*)(pb0 + k0); lb01 = *(const f32x4*)(pb0 + k0 + 4);
    lb10 = *(const f32x4*)(pb1 + k0); lb11 = *(const f32x4*)(pb1 + k0 + 4);
  };
  auto write_tile = [&](int buf) {
    *(f16x8*)&As[buf][wA0] = la0;
    *(f16x8*)&As[buf][wA1] = la1;
    *(f16x8*)&Bs[buf][wA0] = cvt8(lb00, lb01);
    *(f16x8*)&Bs[buf][wA1] = cvt8(lb10, lb11);
  };

  f32x16 acc[4][2];
#pragma unroll
  for (int m = 0; m < 4; ++m)
#pragma unroll
    for (int n = 0; n < 2; ++n) acc[m][n] = (f32x16)0.f;

  const int lane = tid & 63, wv = tid >> 6;
  const int wrow = (wv >> 2) * 128;  // 0,128
  const int wcol = (wv & 3) * 64;    // 0,64,128,192
  const int frow = lane & 31;
  const int kq   = lane >> 5;

  load_tile(0);
  write_tile(0);
  __syncthreads();

  const int NS = FFN / BK;  // 176
  for (int ks = 0; ks < NS; ++ks) {
    int buf = ks & 1;
    if (ks + 1 < NS) load_tile((ks + 1) * BK);
#pragma unroll
    for (int ksub = 0; ksub < 2; ++ksub) {
      const int p = ksub * 2 + kq;
      f16x8 fa[4], fb[2];
#pragma unroll
      for (int m = 0; m < 4; ++m)
        fa[m] = *(const f16x8*)&As[buf][p * PS2 + (wrow + m * 32 + frow) * 8];
#pragma unroll
      for (int n = 0; n < 2; ++n)
        fb[n] = *(const f16x8*)&Bs[buf][p * PS2 + (wcol + n * 32 + frow) * 8];
#pragma unroll
      for (int m = 0; m < 4; ++m)
#pragma unroll
        for (int n = 0; n < 2; ++n)
          acc[m][n] = __builtin_amdgcn_mfma_f32_32x32x16_f16(fa[m], fb[n], acc[m][n], 0, 0, 0);
    }
    if (ks + 1 < NS) write_tile(buf ^ 1);
    __syncthreads();
  }

#pragma unroll
  for (int mi = 0; mi < 4; ++mi) {
#pragma unroll
    for (int ni = 0; ni < 2; ++ni) {
      const int col = (size_t)ct * BN2 + wcol + ni * 32 + frow;
#pragma unroll
      for (int r = 0; r < 16; ++r) {
        int rl = wrow + mi * 32 + 4 * kq + (r & 3) + 8 * (r >> 2);
        int pr = row_pair[rl];
        if (pr >= 0) {
          float v = acc[mi][ni][r] * row_w[rl];
          unsafeAtomicAdd(out + (size_t)(pr >> 1) * HD + col, v);
        }
      }
    }
  }
}

extern "C" void kernel_launch(void* const* d_in, const int* in_sizes, int n_in,
                              void* d_out, int out_size, void* d_ws, size_t ws_size,
                              hipStream_t stream) {
  (void)in_sizes; (void)n_in; (void)out_size; (void)ws_size;
  const float* x    = (const float*)d_in[0];
  const float* wg   = (const float*)d_in[1];
  const float* wge  = (const float*)d_in[2];
  const float* fc11 = (const float*)d_in[3];
  const float* fc12 = (const float*)d_in[4];
  const float* fc2  = (const float*)d_in[5];
  float* out    = (float*)d_out;
  float* logits = out + (size_t)TT * HD;

  char* ws = (char*)d_ws;
  float* wr     = (float*)(ws + OFF_WR);
  int*   cnt    = (int*)(ws + OFF_CNT);
  int*   lists  = (int*)(ws + OFF_LISTS);
  float* tokw   = (float*)(ws + OFF_TOKW);
  _Float16* act = (_Float16*)(ws + OFF_ACT);

  hipMemsetAsync(out, 0, (size_t)TT * HD * sizeof(float), stream);
  hipMemsetAsync(cnt, 0, NE * sizeof(int), stream);

  k_prep<<<dim3((HD * NE + 255) / 256), 256, 0, stream>>>(wg, wge, wr);
  k_router<<<dim3(TT), 256, 0, stream>>>(x, wr, logits, tokw, lists, cnt);
  k_ffn1<<<dim3(TT / BM1, FFN / BN1, NE), 512, 0, stream>>>(x, fc11, fc12, lists, cnt, act);
  k_ffn2<<<dim3(TT / BM2, HD / BN2, NE), 512, 0, stream>>>(act, fc2, lists, cnt, tokw, out);
}

// Round 3
// 3738.017 us; speedup vs baseline: 1.8278x; 1.8278x over previous
//
#include <hip/hip_runtime.h>

#define TT 8192      // max pairs per expert / token count
#define HD 2048
#define FFN 5632
#define NE 8
#define BK 32

// ffn1: 128 (tokens) x 64 (ffn cols) dual-B tile, 4 waves
#define BM1 128
#define BN1 64
#define PSA1 1040    // 128*8 + 16 pad fp16 elems per k-plane (stride 2080B ≡ 32 mod 128)
#define PSB1 528     // 64*8 + 16 pad (1056B ≡ 32 mod 128)
// ffn2: 128 x 128 tile, 4 waves
#define BM2 128
#define BN2 128
#define PS2  1040

typedef float f32x4 __attribute__((ext_vector_type(4)));
typedef _Float16 f16x8 __attribute__((ext_vector_type(8)));

// workspace layout (bytes)
#define OFF_WR    0u
#define OFF_CNT   65536u
#define OFF_LISTS 66048u
#define OFF_TOKW  328192u
#define OFF_ACT   1048576u   // 16384*5632 f16

__device__ __forceinline__ f16x8 cvt8(f32x4 a, f32x4 b) {
  f16x8 r;
  r[0] = (_Float16)a[0]; r[1] = (_Float16)a[1]; r[2] = (_Float16)a[2]; r[3] = (_Float16)a[3];
  r[4] = (_Float16)b[0]; r[5] = (_Float16)b[1]; r[6] = (_Float16)b[2]; r[7] = (_Float16)b[3];
  return r;
}

__global__ __launch_bounds__(256) void k_prep(const float* __restrict__ wg,
                                              const float* __restrict__ wge,
                                              float* __restrict__ wr) {
  int i = blockIdx.x * 256 + threadIdx.x;
  if (i < HD * NE) wr[i] = 0.5f * (wge[i] + wg[i]);
}

__global__ __launch_bounds__(256) void k_router(const float* __restrict__ x,
                                                const float* __restrict__ wr,
                                                float* __restrict__ logits,
                                                float* __restrict__ tokw,
                                                int* __restrict__ lists,
                                                int* __restrict__ cnt) {
  const int t = blockIdx.x, tid = threadIdx.x;
  const float* xr = x + (size_t)t * HD;
  float acc[NE];
#pragma unroll
  for (int e = 0; e < NE; ++e) acc[e] = 0.f;
  for (int h = tid; h < HD; h += 256) {
    float xv = xr[h];
    const float* w = wr + h * NE;
#pragma unroll
    for (int e = 0; e < NE; ++e) acc[e] = fmaf(xv, w[e], acc[e]);
  }
#pragma unroll
  for (int e = 0; e < NE; ++e)
#pragma unroll
    for (int off = 32; off; off >>= 1)
      acc[e] += __shfl_xor(acc[e], off, 64);
  __shared__ float red[4][NE];
  int wv = tid >> 6;
  if ((tid & 63) == 0)
    for (int e = 0; e < NE; ++e) red[wv][e] = acc[e];
  __syncthreads();
  if (tid == 0) {
    float l[NE];
#pragma unroll
    for (int e = 0; e < NE; ++e) l[e] = red[0][e] + red[1][e] + red[2][e] + red[3][e];
#pragma unroll
    for (int e = 0; e < NE; ++e) logits[(size_t)t * NE + e] = l[e];
    int i0 = 0;
    for (int e = 1; e < NE; ++e) if (l[e] > l[i0]) i0 = e;
    int i1 = -1;
    for (int e = 0; e < NE; ++e) if (e != i0 && (i1 < 0 || l[e] > l[i1])) i1 = e;
    float p1 = __expf(l[i1] - l[i0]);
    float s = 1.f + p1;
    tokw[t * 2]     = 1.f / s;
    tokw[t * 2 + 1] = p1 / s;
    int q0 = atomicAdd(&cnt[i0], 1);
    lists[i0 * TT + q0] = t * 2;
    int q1 = atomicAdd(&cnt[i1], 1);
    lists[i1 * TT + q1] = t * 2 + 1;
  }
}

// ---------------- Stage A: act = silu(x@fc1_1^T) * (x@fc1_2^T) -> fp16 -------------
// 4 waves as 2x2 over (BM1=128, BN1=64); wave tile 64x32 dual; mfma 16x16x32.
__global__ __launch_bounds__(256, 3) void k_ffn1(const float* __restrict__ x,
                                                 const float* __restrict__ fc11,
                                                 const float* __restrict__ fc12,
                                                 const int* __restrict__ lists,
                                                 const int* __restrict__ cnt,
                                                 _Float16* __restrict__ act) {
  const int rt = blockIdx.x, ct = blockIdx.y, e = blockIdx.z;
  const int count = cnt[e];
  if (rt * BM1 >= count) return;
  const int tid = threadIdx.x;

  __shared__ __align__(16) _Float16 As[2][4 * PSA1];
  __shared__ __align__(16) _Float16 B1s[2][4 * PSB1];
  __shared__ __align__(16) _Float16 B2s[2][4 * PSB1];
  __shared__ int row_pair[BM1];

  if (tid < BM1) {
    int rg = rt * BM1 + tid;
    row_pair[tid] = (rg < count) ? lists[e * TT + rg] : -1;
  }
  __syncthreads();

  // staging: chunk = 8 consecutive k at one row.
  const int sr  = tid >> 2;         // 0..63
  const int skg = tid & 3;          // k-chunk (plane)
  const int sc8 = skg * 8;
  const int pr0 = row_pair[sr], pr1 = row_pair[sr + 64];
  const float* pa0 = (pr0 >= 0) ? x + (size_t)(pr0 >> 1) * HD + sc8 : nullptr;
  const float* pa1 = (pr1 >= 0) ? x + (size_t)(pr1 >> 1) * HD + sc8 : nullptr;
  const float* pb1 = fc11 + ((size_t)e * FFN + (size_t)ct * BN1 + sr) * HD + sc8;
  const float* pb2 = fc12 + ((size_t)e * FFN + (size_t)ct * BN1 + sr) * HD + sc8;
  const int wA0 = skg * PSA1 + sr * 8;
  const int wA1 = skg * PSA1 + (sr + 64) * 8;
  const int wB  = skg * PSB1 + sr * 8;

  const f32x4 z4 = {0.f, 0.f, 0.f, 0.f};
  f32x4 a00, a01, a10, a11, b10, b11, b20, b21;
  auto load_tile = [&](int k0) {
    a00 = pa0 ? *(const f32x4*)(pa0 + k0) : z4;
    a01 = pa0 ? *(const f32x4*)(pa0 + k0 + 4) : z4;
    a10 = pa1 ? *(const f32x4*)(pa1 + k0) : z4;
    a11 = pa1 ? *(const f32x4*)(pa1 + k0 + 4) : z4;
    b10 = *(const f32x4*)(pb1 + k0); b11 = *(const f32x4*)(pb1 + k0 + 4);
    b20 = *(const f32x4*)(pb2 + k0); b21 = *(const f32x4*)(pb2 + k0 + 4);
  };
  auto write_tile = [&](int buf) {
    *(f16x8*)&As[buf][wA0]  = cvt8(a00, a01);
    *(f16x8*)&As[buf][wA1]  = cvt8(a10, a11);
    *(f16x8*)&B1s[buf][wB]  = cvt8(b10, b11);
    *(f16x8*)&B2s[buf][wB]  = cvt8(b20, b21);
  };

  f32x4 acc1[4][2], acc2[4][2];
#pragma unroll
  for (int m = 0; m < 4; ++m)
#pragma unroll
    for (int n = 0; n < 2; ++n) { acc1[m][n] = z4; acc2[m][n] = z4; }

  const int lane = tid & 63, wv = tid >> 6;
  const int wrow = (wv >> 1) * 64;   // 0,64
  const int wcol = (wv & 1) * 32;    // 0,32
  const int fr = lane & 15;
  const int kq = lane >> 4;          // k-plane

  load_tile(0);
  write_tile(0);
  __syncthreads();

  const int NS = HD / BK;  // 64
  for (int ks = 0; ks < NS; ++ks) {
    int buf = ks & 1;
    if (ks + 1 < NS) load_tile((ks + 1) * BK);
    f16x8 fa[4], fb1[2], fb2[2];
#pragma unroll
    for (int m = 0; m < 4; ++m)
      fa[m] = *(const f16x8*)&As[buf][kq * PSA1 + (wrow + m * 16 + fr) * 8];
#pragma unroll
    for (int n = 0; n < 2; ++n) {
      fb1[n] = *(const f16x8*)&B1s[buf][kq * PSB1 + (wcol + n * 16 + fr) * 8];
      fb2[n] = *(const f16x8*)&B2s[buf][kq * PSB1 + (wcol + n * 16 + fr) * 8];
    }
#pragma unroll
    for (int m = 0; m < 4; ++m)
#pragma unroll
      for (int n = 0; n < 2; ++n) {
        acc1[m][n] = __builtin_amdgcn_mfma_f32_16x16x32_f16(fa[m], fb1[n], acc1[m][n], 0, 0, 0);
        acc2[m][n] = __builtin_amdgcn_mfma_f32_16x16x32_f16(fa[m], fb2[n], acc2[m][n], 0, 0, 0);
      }
    if (ks + 1 < NS) write_tile(buf ^ 1);
    __syncthreads();
  }

  const int rbase = wrow + kq * 4;
#pragma unroll
  for (int m = 0; m < 4; ++m) {
#pragma unroll
    for (int n = 0; n < 2; ++n) {
      const int col = ct * BN1 + wcol + n * 16 + fr;
#pragma unroll
      for (int j = 0; j < 4; ++j) {
        int rl = rbase + m * 16 + j;
        int pr = row_pair[rl];
        if (pr >= 0) {
          float h1 = acc1[m][n][j], h2 = acc2[m][n][j];
          float sv = h1 / (1.f + __expf(-h1));
          act[(size_t)pr * FFN + col] = (_Float16)(sv * h2);
        }
      }
    }
  }
}

// ---------------- Stage B: out += w * (act @ fc2^T) --------------------------------
// 4 waves as 2x2 over (BM2=128, BN2=128); wave tile 64x64; mfma 16x16x32.
__global__ __launch_bounds__(256, 3) void k_ffn2(const _Float16* __restrict__ act,
                                                 const float* __restrict__ fc2,
                                                 const int* __restrict__ lists,
                                                 const int* __restrict__ cnt,
                                                 const float* __restrict__ tokw,
                                                 float* __restrict__ out) {
  const int rt = blockIdx.x, ct = blockIdx.y, e = blockIdx.z;
  const int count = cnt[e];
  if (rt * BM2 >= count) return;
  const int tid = threadIdx.x;

  __shared__ __align__(16) _Float16 As[2][4 * PS2];
  __shared__ __align__(16) _Float16 Bs[2][4 * PS2];
  __shared__ int row_pair[BM2];
  __shared__ float row_w[BM2];

  if (tid < BM2) {
    int rg = rt * BM2 + tid;
    int pr = (rg < count) ? lists[e * TT + rg] : -1;
    row_pair[tid] = pr;
    row_w[tid] = (pr >= 0) ? tokw[pr] : 0.f;
  }
  __syncthreads();

  const int sr  = tid >> 2;
  const int skg = tid & 3;
  const int sc8 = skg * 8;
  const int pr0 = row_pair[sr], pr1 = row_pair[sr + 64];
  const _Float16* pa0 = (pr0 >= 0) ? act + (size_t)pr0 * FFN + sc8 : nullptr;
  const _Float16* pa1 = (pr1 >= 0) ? act + (size_t)pr1 * FFN + sc8 : nullptr;
  const float* pb0 = fc2 + ((size_t)e * HD + (size_t)ct * BN2 + sr) * FFN + sc8;
  const float* pb1 = fc2 + ((size_t)e * HD + (size_t)ct * BN2 + sr + 64) * FFN + sc8;
  const int wA0 = skg * PS2 + sr * 8;
  const int wA1 = skg * PS2 + (sr + 64) * 8;

  const f16x8 z8 = (f16x8)(_Float16)0;
  f16x8 la0, la1;
  f32x4 lb00, lb01, lb10, lb11;
  auto load_tile = [&](int k0) {
    la0 = pa0 ? *(const f16x8*)(pa0 + k0) : z8;
    la1 = pa1 ? *(const f16x8*)(pa1 + k0) : z8;
    lb00 = *(const f32x4*)(pb0 + k0); lb01 = *(const f32x4*)(pb0 + k0 + 4);
    lb10 = *(const f32x4*)(pb1 + k0); lb11 = *(const f32x4*)(pb1 + k0 + 4);
  };
  auto write_tile = [&](int buf) {
    *(f16x8*)&As[buf][wA0] = la0;
    *(f16x8*)&As[buf][wA1] = la1;
    *(f16x8*)&Bs[buf][wA0] = cvt8(lb00, lb01);
    *(f16x8*)&Bs[buf][wA1] = cvt8(lb10, lb11);
  };

  const f32x4 z4 = {0.f, 0.f, 0.f, 0.f};
  f32x4 acc[4][4];
#pragma unroll
  for (int m = 0; m < 4; ++m)
#pragma unroll
    for (int n = 0; n < 4; ++n) acc[m][n] = z4;

  const int lane = tid & 63, wv = tid >> 6;
  const int wrow = (wv >> 1) * 64;
  const int wcol = (wv & 1) * 64;
  const int fr = lane & 15;
  const int kq = lane >> 4;

  load_tile(0);
  write_tile(0);
  __syncthreads();

  const int NS = FFN / BK;  // 176
  for (int ks = 0; ks < NS; ++ks) {
    int buf = ks & 1;
    if (ks + 1 < NS) load_tile((ks + 1) * BK);
    f16x8 fa[4], fb[4];
#pragma unroll
    for (int m = 0; m < 4; ++m)
      fa[m] = *(const f16x8*)&As[buf][kq * PS2 + (wrow + m * 16 + fr) * 8];
#pragma unroll
    for (int n = 0; n < 4; ++n)
      fb[n] = *(const f16x8*)&Bs[buf][kq * PS2 + (wcol + n * 16 + fr) * 8];
#pragma unroll
    for (int m = 0; m < 4; ++m)
#pragma unroll
      for (int n = 0; n < 4; ++n)
        acc[m][n] = __builtin_amdgcn_mfma_f32_16x16x32_f16(fa[m], fb[n], acc[m][n], 0, 0, 0);
    if (ks + 1 < NS) write_tile(buf ^ 1);
    __syncthreads();
  }

  const int rbase = wrow + kq * 4;
#pragma unroll
  for (int m = 0; m < 4; ++m) {
#pragma unroll
    for (int n = 0; n < 4; ++n) {
      const int col = ct * BN2 + wcol + n * 16 + fr;
#pragma unroll
      for (int j = 0; j < 4; ++j) {
        int rl = rbase + m * 16 + j;
        int pr = row_pair[rl];
        if (pr >= 0) {
          float v = acc[m][n][j] * row_w[rl];
          unsafeAtomicAdd(out + (size_t)(pr >> 1) * HD + col, v);
        }
      }
    }
  }
}

extern "C" void kernel_launch(void* const* d_in, const int* in_sizes, int n_in,
                              void* d_out, int out_size, void* d_ws, size_t ws_size,
                              hipStream_t stream) {
  (void)in_sizes; (void)n_in; (void)out_size; (void)ws_size;
  const float* x    = (const float*)d_in[0];
  const float* wg   = (const float*)d_in[1];
  const float* wge  = (const float*)d_in[2];
  const float* fc11 = (const float*)d_in[3];
  const float* fc12 = (const float*)d_in[4];
  const float* fc2  = (const float*)d_in[5];
  float* out    = (float*)d_out;
  float* logits = out + (size_t)TT * HD;

  char* ws = (char*)d_ws;
  float* wr     = (float*)(ws + OFF_WR);
  int*   cnt    = (int*)(ws + OFF_CNT);
  int*   lists  = (int*)(ws + OFF_LISTS);
  float* tokw   = (float*)(ws + OFF_TOKW);
  _Float16* act = (_Float16*)(ws + OFF_ACT);

  hipMemsetAsync(out, 0, (size_t)TT * HD * sizeof(float), stream);
  hipMemsetAsync(cnt, 0, NE * sizeof(int), stream);

  k_prep<<<dim3((HD * NE + 255) / 256), 256, 0, stream>>>(wg, wge, wr);
  k_router<<<dim3(TT), 256, 0, stream>>>(x, wr, logits, tokw, lists, cnt);
  k_ffn1<<<dim3(TT / BM1, FFN / BN1, NE), 256, 0, stream>>>(x, fc11, fc12, lists, cnt, act);
  k_ffn2<<<dim3(TT / BM2, HD / BN2, NE), 256, 0, stream>>>(act, fc2, lists, cnt, tokw, out);
}

// Round 4
// 2954.250 us; speedup vs baseline: 2.3128x; 1.2653x over previous
//
#include <hip/hip_runtime.h>
#include <stdint.h>

#define TT 8192
#define HD 2048
#define FFN 5632
#define NE 8
#define BK 32

typedef float f32x4 __attribute__((ext_vector_type(4)));
typedef _Float16 f16x8 __attribute__((ext_vector_type(8)));
typedef unsigned int u32;

// workspace layout (bytes)
#define OFF_WR    0ul
#define OFF_CNT   65536ul
#define OFF_LISTS 66048ul
#define OFF_TOKW  328192ul
#define OFF_ACT   1048576ul                    // 16384*5632*2   = 184549376
#define OFF_XH    (OFF_ACT + 184549376ul)      // 8192*2048*2    = 33554432
#define OFF_W1H   (OFF_XH + 33554432ul)        // 8*5632*2048*2  = 184549376
#define OFF_W2H   (OFF_W1H + 184549376ul)      // 8*5632*2048*2
#define OFF_W3H   OFF_W1H                      // fc2h reuses W1H (stream-ordered after ffn1)
// total need = OFF_W2H + 184549376 = 588251136 bytes (~561 MiB)

__device__ __forceinline__ void gl_lds16(const void* g, void* s) {
  __builtin_amdgcn_global_load_lds((const __attribute__((address_space(1))) u32*)g,
                                   (__attribute__((address_space(3))) u32*)s, 16, 0, 0);
}

__device__ __forceinline__ f16x8 cvt8(f32x4 a, f32x4 b) {
  f16x8 r;
  r[0] = (_Float16)a[0]; r[1] = (_Float16)a[1]; r[2] = (_Float16)a[2]; r[3] = (_Float16)a[3];
  r[4] = (_Float16)b[0]; r[5] = (_Float16)b[1]; r[6] = (_Float16)b[2]; r[7] = (_Float16)b[3];
  return r;
}

__global__ __launch_bounds__(256) void k_cvt(const float* __restrict__ in,
                                             _Float16* __restrict__ out, long n8) {
  long i = (long)blockIdx.x * 256 + threadIdx.x;
  const long stride = (long)gridDim.x * 256;
  for (; i < n8; i += stride) {
    f32x4 a = ((const f32x4*)in)[i * 2];
    f32x4 b = ((const f32x4*)in)[i * 2 + 1];
    ((f16x8*)out)[i] = cvt8(a, b);
  }
}

__global__ __launch_bounds__(256) void k_prep(const float* __restrict__ wg,
                                              const float* __restrict__ wge,
                                              float* __restrict__ wr) {
  int i = blockIdx.x * 256 + threadIdx.x;
  if (i < HD * NE) wr[i] = 0.5f * (wge[i] + wg[i]);
}

__global__ __launch_bounds__(256) void k_router(const float* __restrict__ x,
                                                const float* __restrict__ wr,
                                                float* __restrict__ logits,
                                                float* __restrict__ tokw,
                                                int* __restrict__ lists,
                                                int* __restrict__ cnt) {
  const int t = blockIdx.x, tid = threadIdx.x;
  const float* xr = x + (size_t)t * HD;
  float acc[NE];
#pragma unroll
  for (int e = 0; e < NE; ++e) acc[e] = 0.f;
  for (int h = tid; h < HD; h += 256) {
    float xv = xr[h];
    const float* w = wr + h * NE;
#pragma unroll
    for (int e = 0; e < NE; ++e) acc[e] = fmaf(xv, w[e], acc[e]);
  }
#pragma unroll
  for (int e = 0; e < NE; ++e)
#pragma unroll
    for (int off = 32; off; off >>= 1)
      acc[e] += __shfl_xor(acc[e], off, 64);
  __shared__ float red[4][NE];
  int wv = tid >> 6;
  if ((tid & 63) == 0)
    for (int e = 0; e < NE; ++e) red[wv][e] = acc[e];
  __syncthreads();
  if (tid == 0) {
    float l[NE];
#pragma unroll
    for (int e = 0; e < NE; ++e) l[e] = red[0][e] + red[1][e] + red[2][e] + red[3][e];
#pragma unroll
    for (int e = 0; e < NE; ++e) logits[(size_t)t * NE + e] = l[e];
    int i0 = 0;
    for (int e = 1; e < NE; ++e) if (l[e] > l[i0]) i0 = e;
    int i1 = -1;
    for (int e = 0; e < NE; ++e) if (e != i0 && (i1 < 0 || l[e] > l[i1])) i1 = e;
    float p1 = __expf(l[i1] - l[i0]);
    float s = 1.f + p1;
    tokw[t * 2]     = 1.f / s;
    tokw[t * 2 + 1] = p1 / s;
    int q0 = atomicAdd(&cnt[i0], 1);
    lists[i0 * TT + q0] = t * 2;
    int q1 = atomicAdd(&cnt[i1], 1);
    lists[i1 * TT + q1] = t * 2 + 1;
  }
}

// ---- Stage A: act = silu(xh@w1h^T) * (xh@w2h^T) -> fp16. m97-structure. ----
// tile 128(M) x 64(N dual), BK=32, 4 waves 2x2, wave 64x32 dual, mfma 16x16x32.
__global__ __launch_bounds__(256, 3) void k_ffn1(const _Float16* __restrict__ xh,
                                                 const _Float16* __restrict__ w1h,
                                                 const _Float16* __restrict__ w2h,
                                                 const int* __restrict__ lists,
                                                 const int* __restrict__ cnt,
                                                 _Float16* __restrict__ act) {
  const int rt = blockIdx.x, ct = blockIdx.y, e = blockIdx.z;
  const int count = cnt[e];
  if (rt * 128 >= count) return;
  const int tid = threadIdx.x, lane = tid & 63, wv = tid >> 6;

  __shared__ __align__(16) _Float16 As[2][128 * 32];
  __shared__ __align__(16) _Float16 B1s[2][64 * 32];
  __shared__ __align__(16) _Float16 B2s[2][64 * 32];
  __shared__ int row_pair[128];

  if (tid < 128) {
    int rg = rt * 128 + tid;
    row_pair[tid] = (rg < count) ? lists[e * TT + rg] : -1;
  }
  __syncthreads();

  // per-lane global sources: 16 rows/instr, 4 lanes/row, 16B/lane (k-chunk of 8)
  const int lr = lane >> 2, lc = (lane & 3) * 8;
  const int ar0 = wv * 32 + lr, ar1 = ar0 + 16;
  const int p0 = row_pair[ar0], p1 = row_pair[ar1];
  const _Float16* pa0 = xh + (size_t)((p0 >= 0) ? (p0 >> 1) : 0) * HD + lc;
  const _Float16* pa1 = xh + (size_t)((p1 >= 0) ? (p1 >> 1) : 0) * HD + lc;
  const int brow = ct * 64 + wv * 16 + lr;
  const _Float16* pb1 = w1h + ((size_t)e * FFN + brow) * HD + lc;
  const _Float16* pb2 = w2h + ((size_t)e * FFN + brow) * HD + lc;

  auto stage = [&](int buf, int koff) {
    gl_lds16(pa0 + koff, &As[buf][wv * 1024]);
    gl_lds16(pa1 + koff, &As[buf][wv * 1024 + 512]);
    gl_lds16(pb1 + koff, &B1s[buf][wv * 512]);
    gl_lds16(pb2 + koff, &B2s[buf][wv * 512]);
  };

  const f32x4 z4 = {0.f, 0.f, 0.f, 0.f};
  f32x4 acc1[4][2], acc2[4][2];
#pragma unroll
  for (int m = 0; m < 4; ++m)
#pragma unroll
    for (int n = 0; n < 2; ++n) { acc1[m][n] = z4; acc2[m][n] = z4; }

  const int fr = lane & 15, kq = lane >> 4;
  const int wrow = (wv >> 1) * 64, wcol = (wv & 1) * 32;

  stage(0, 0);
  __syncthreads();

  const int NS = HD / BK;  // 64
  for (int ks = 0; ks < NS; ++ks) {
    const int buf = ks & 1;
    if (ks + 1 < NS) stage(buf ^ 1, (ks + 1) * BK);
    f16x8 fa[4], fb1[2], fb2[2];
#pragma unroll
    for (int m = 0; m < 4; ++m)
      fa[m] = *(const f16x8*)&As[buf][(wrow + m * 16 + fr) * 32 + kq * 8];
#pragma unroll
    for (int n = 0; n < 2; ++n) {
      fb1[n] = *(const f16x8*)&B1s[buf][(wcol + n * 16 + fr) * 32 + kq * 8];
      fb2[n] = *(const f16x8*)&B2s[buf][(wcol + n * 16 + fr) * 32 + kq * 8];
    }
#pragma unroll
    for (int m = 0; m < 4; ++m)
#pragma unroll
      for (int n = 0; n < 2; ++n) {
        acc1[m][n] = __builtin_amdgcn_mfma_f32_16x16x32_f16(fa[m], fb1[n], acc1[m][n], 0, 0, 0);
        acc2[m][n] = __builtin_amdgcn_mfma_f32_16x16x32_f16(fa[m], fb2[n], acc2[m][n], 0, 0, 0);
      }
    __syncthreads();
  }

  const int rbase = wrow + kq * 4;
#pragma unroll
  for (int m = 0; m < 4; ++m) {
#pragma unroll
    for (int n = 0; n < 2; ++n) {
      const int col = ct * 64 + wcol + n * 16 + fr;
#pragma unroll
      for (int j = 0; j < 4; ++j) {
        int rl = rbase + m * 16 + j;
        int pr = row_pair[rl];
        if (pr >= 0) {
          float h1 = acc1[m][n][j], h2 = acc2[m][n][j];
          float sv = h1 / (1.f + __expf(-h1));
          act[(size_t)pr * FFN + col] = (_Float16)(sv * h2);
        }
      }
    }
  }
}

// ---- Stage B: out += w * (act @ fc2h^T). tile 128x128, BK=32, wave 64x64. ----
__global__ __launch_bounds__(256, 3) void k_ffn2(const _Float16* __restrict__ act,
                                                 const _Float16* __restrict__ w3h,
                                                 const int* __restrict__ lists,
                                                 const int* __restrict__ cnt,
                                                 const float* __restrict__ tokw,
                                                 float* __restrict__ out) {
  const int rt = blockIdx.x, ct = blockIdx.y, e = blockIdx.z;
  const int count = cnt[e];
  if (rt * 128 >= count) return;
  const int tid = threadIdx.x, lane = tid & 63, wv = tid >> 6;

  __shared__ __align__(16) _Float16 As[2][128 * 32];
  __shared__ __align__(16) _Float16 Bs[2][128 * 32];
  __shared__ int row_pair[128];
  __shared__ float row_w[128];

  if (tid < 128) {
    int rg = rt * 128 + tid;
    int pr = (rg < count) ? lists[e * TT + rg] : -1;
    row_pair[tid] = pr;
    row_w[tid] = (pr >= 0) ? tokw[pr] : 0.f;
  }
  __syncthreads();

  const int lr = lane >> 2, lc = (lane & 3) * 8;
  const int ar0 = wv * 32 + lr, ar1 = ar0 + 16;
  const int p0 = row_pair[ar0], p1 = row_pair[ar1];
  const _Float16* pa0 = act + (size_t)((p0 >= 0) ? p0 : 0) * FFN + lc;
  const _Float16* pa1 = act + (size_t)((p1 >= 0) ? p1 : 0) * FFN + lc;
  const int br0 = ct * 128 + wv * 32 + lr, br1 = br0 + 16;
  const _Float16* pb0 = w3h + ((size_t)e * HD + br0) * FFN + lc;
  const _Float16* pb1 = w3h + ((size_t)e * HD + br1) * FFN + lc;

  auto stage = [&](int buf, int koff) {
    gl_lds16(pa0 + koff, &As[buf][wv * 1024]);
    gl_lds16(pa1 + koff, &As[buf][wv * 1024 + 512]);
    gl_lds16(pb0 + koff, &Bs[buf][wv * 1024]);
    gl_lds16(pb1 + koff, &Bs[buf][wv * 1024 + 512]);
  };

  const f32x4 z4 = {0.f, 0.f, 0.f, 0.f};
  f32x4 acc[4][4];
#pragma unroll
  for (int m = 0; m < 4; ++m)
#pragma unroll
    for (int n = 0; n < 4; ++n) acc[m][n] = z4;

  const int fr = lane & 15, kq = lane >> 4;
  const int wrow = (wv >> 1) * 64, wcol = (wv & 1) * 64;

  stage(0, 0);
  __syncthreads();

  const int NS = FFN / BK;  // 176
  for (int ks = 0; ks < NS; ++ks) {
    const int buf = ks & 1;
    if (ks + 1 < NS) stage(buf ^ 1, (ks + 1) * BK);
    f16x8 fa[4], fb[4];
#pragma unroll
    for (int m = 0; m < 4; ++m)
      fa[m] = *(const f16x8*)&As[buf][(wrow + m * 16 + fr) * 32 + kq * 8];
#pragma unroll
    for (int n = 0; n < 4; ++n)
      fb[n] = *(const f16x8*)&Bs[buf][(wcol + n * 16 + fr) * 32 + kq * 8];
#pragma unroll
    for (int m = 0; m < 4; ++m)
#pragma unroll
      for (int n = 0; n < 4; ++n)
        acc[m][n] = __builtin_amdgcn_mfma_f32_16x16x32_f16(fa[m], fb[n], acc[m][n], 0, 0, 0);
    __syncthreads();
  }

  const int rbase = wrow + kq * 4;
#pragma unroll
  for (int m = 0; m < 4; ++m) {
#pragma unroll
    for (int n = 0; n < 4; ++n) {
      const int col = ct * 128 + wcol + n * 16 + fr;
#pragma unroll
      for (int j = 0; j < 4; ++j) {
        int rl = rbase + m * 16 + j;
        int pr = row_pair[rl];
        if (pr >= 0) {
          float v = acc[m][n][j] * row_w[rl];
          unsafeAtomicAdd(out + (size_t)(pr >> 1) * HD + col, v);
        }
      }
    }
  }
}

extern "C" void kernel_launch(void* const* d_in, const int* in_sizes, int n_in,
                              void* d_out, int out_size, void* d_ws, size_t ws_size,
                              hipStream_t stream) {
  (void)in_sizes; (void)n_in; (void)out_size; (void)ws_size;
  const float* x    = (const float*)d_in[0];
  const float* wg   = (const float*)d_in[1];
  const float* wge  = (const float*)d_in[2];
  const float* fc11 = (const float*)d_in[3];
  const float* fc12 = (const float*)d_in[4];
  const float* fc2  = (const float*)d_in[5];
  float* out    = (float*)d_out;
  float* logits = out + (size_t)TT * HD;

  char* ws = (char*)d_ws;
  float* wr      = (float*)(ws + OFF_WR);
  int*   cnt     = (int*)(ws + OFF_CNT);
  int*   lists   = (int*)(ws + OFF_LISTS);
  float* tokw    = (float*)(ws + OFF_TOKW);
  _Float16* act  = (_Float16*)(ws + OFF_ACT);
  _Float16* xh   = (_Float16*)(ws + OFF_XH);
  _Float16* w1h  = (_Float16*)(ws + OFF_W1H);
  _Float16* w2h  = (_Float16*)(ws + OFF_W2H);
  _Float16* w3h  = (_Float16*)(ws + OFF_W3H);

  hipMemsetAsync(out, 0, (size_t)TT * HD * sizeof(float), stream);
  hipMemsetAsync(cnt, 0, NE * sizeof(int), stream);

  k_prep<<<dim3((HD * NE + 255) / 256), 256, 0, stream>>>(wg, wge, wr);
  k_router<<<dim3(TT), 256, 0, stream>>>(x, wr, logits, tokw, lists, cnt);

  const long nX  = (long)TT * HD / 8;
  const long nW1 = (long)NE * FFN * HD / 8;
  k_cvt<<<dim3(2048), 256, 0, stream>>>(x, xh, nX);
  k_cvt<<<dim3(2048), 256, 0, stream>>>(fc11, w1h, nW1);
  k_cvt<<<dim3(2048), 256, 0, stream>>>(fc12, w2h, nW1);

  k_ffn1<<<dim3(TT / 128, FFN / 64, NE), 256, 0, stream>>>(xh, w1h, w2h, lists, cnt, act);

  // fc2h reuses W1H region — stream-ordered after ffn1 finished reading w1h
  k_cvt<<<dim3(2048), 256, 0, stream>>>(fc2, w3h, nW1);

  k_ffn2<<<dim3(TT / 128, HD / 128, NE), 256, 0, stream>>>(act, w3h, lists, cnt, tokw, out);
}